// Round 10
// baseline (301.097 us; speedup 1.0000x reference)
//
#include <hip/hip_runtime.h>
#include <hip/hip_bf16.h>

using f32x4  = __attribute__((ext_vector_type(4))) float;
using i32x4  = __attribute__((ext_vector_type(4))) int;
using bf16x8 = __attribute__((ext_vector_type(8))) short;
using bf16x4 = __attribute__((ext_vector_type(4))) short;

constexpr int BATCH = 8, SEQ = 1024, DIM = 768, NHEAD = 12, HDIM = 64;
constexpr int MROWS = BATCH * SEQ;   // 8192

__device__ __forceinline__ short f2bf(float f) {
    union { float f; unsigned u; } x; x.f = f;
    unsigned r = (x.u + 0x7fffu + ((x.u >> 16) & 1u)) >> 16;
    return (short)r;
}
__device__ __forceinline__ float fexp2(float x) { return __builtin_amdgcn_exp2f(x); }

__device__ __forceinline__ bf16x8 cvt8(const float* p) {
    const f32x4 x0 = *(const f32x4*)p;
    const f32x4 x1 = *(const f32x4*)(p + 4);
    bf16x8 r;
    #pragma unroll
    for (int j = 0; j < 4; ++j) { r[j] = f2bf(x0[j]); r[4 + j] = f2bf(x1[j]); }
    return r;
}

// K fragment-order: attn reads kb[c][ks] at kt*4096 + c*1024 + ks*512 + lane*8
// (l16 = key&15, lg = hd-slot). Element (tok, dd):
__device__ __forceinline__ long kfrag_addr(int tok, int dd) {
    return ((long)(tok >> 6)) * 4096 + ((tok & 63) >> 4) * 1024 + (dd >> 5) * 512
         + ((dd >> 3) & 3) * 128 + (tok & 15) * 8 + (dd & 7);
}
// V fragment-order: attn reads vb[df][ks] at kt*4096 + df*1024 + ks*512 + lane*8
// (l16 = hd&15, lg = key-slot). Element (tok, dd):
__device__ __forceinline__ long vfrag_addr(int tok, int dd) {
    return ((long)(tok >> 6)) * 4096 + (dd >> 4) * 1024 + ((tok >> 5) & 1) * 512
         + ((tok >> 3) & 3) * 128 + (dd & 15) * 8 + (tok & 7);
}

// weights-only bf16 prepass (tiny, L2-hot panels reused 64x by gemm blocks)
__global__ __launch_bounds__(256)
void cvt_w(const float* __restrict__ Wq, const float* __restrict__ Wk,
           const float* __restrict__ Wv, const float* __restrict__ Wo,
           short* __restrict__ Wqb, short* __restrict__ Wkb,
           short* __restrict__ Wvb, short* __restrict__ Wob, int n8) {
    const int stride = gridDim.x * 256;
    for (int i = blockIdx.x * 256 + threadIdx.x; i < n8; i += stride) {
        const long base = (long)i * 8;
        *(bf16x8*)(Wqb + base) = cvt8(Wq + base);
        *(bf16x8*)(Wkb + base) = cvt8(Wk + base);
        *(bf16x8*)(Wvb + base) = cvt8(Wv + base);
        *(bf16x8*)(Wob + base) = cvt8(Wo + base);
    }
}

// Fused Q/K/V projection, A staged DIRECTLY from fp32 (T14: issue-early,
// cvt+write-late), W from bf16. sub = bid%3 interleave for co-residency.
__global__ __launch_bounds__(256, 4)
void gemm_qkv(const float* __restrict__ qf, const float* __restrict__ kf,
              const float* __restrict__ vf,
              const short* __restrict__ Wqb, const short* __restrict__ Wkb,
              const short* __restrict__ Wvb,
              const float* __restrict__ bq, const float* __restrict__ bk,
              const float* __restrict__ bv,
              short* __restrict__ Qp, short* __restrict__ Kp, short* __restrict__ Vp) {
    constexpr int K  = DIM;
    constexpr int NT = DIM / 128;
    __shared__ short As[128][72];
    __shared__ short Bs[128][72];

    const int sub = blockIdx.x % 3;
    const int bid = blockIdx.x / 3;
    const float* A = sub == 0 ? qf : sub == 1 ? kf : vf;
    const short* W = sub == 0 ? Wqb : sub == 1 ? Wkb : Wvb;
    const float* bias = sub == 0 ? bq : sub == 1 ? bk : bv;

    const int bm = bid / NT, bn = bid % NT;
    const int m0 = bm * 128, n0 = bn * 128;
    const int t = threadIdx.x;
    const int lane = t & 63, w = t >> 6;
    const int wm = (w >> 1) * 64, wn = (w & 1) * 64;
    const int l16 = lane & 15, lg = lane >> 4;

    const int sr = t >> 1, sc = (t & 1) * 16;
    const float* aptr = A + (long)(m0 + sr) * K + sc;
    const short* wptr = W + (long)(n0 + sr) * K + sc;

    // prologue: tile 0 staging regs
    f32x4 ra[4];
    #pragma unroll
    for (int i = 0; i < 4; ++i) ra[i] = *(const f32x4*)(aptr + i * 4);
    bf16x8 rw0 = *(const bf16x8*)(wptr);
    bf16x8 rw1 = *(const bf16x8*)(wptr + 8);

    f32x4 acc[4][4] = {};

    for (int k0 = 0; k0 < K; k0 += 32) {
        // cvt + write staged tile (data arrived during previous compute)
        short tb[16];
        #pragma unroll
        for (int i = 0; i < 4; ++i)
            #pragma unroll
            for (int j = 0; j < 4; ++j) tb[i * 4 + j] = f2bf(ra[i][j]);
        *(bf16x8*)&As[sr][sc]     = *(bf16x8*)&tb[0];
        *(bf16x8*)&As[sr][sc + 8] = *(bf16x8*)&tb[8];
        *(bf16x8*)&Bs[sr][sc]     = rw0;
        *(bf16x8*)&Bs[sr][sc + 8] = rw1;
        // issue next tile loads (consumed at top of NEXT iter)
        if (k0 + 32 < K) {
            #pragma unroll
            for (int i = 0; i < 4; ++i) ra[i] = *(const f32x4*)(aptr + k0 + 32 + i * 4);
            rw0 = *(const bf16x8*)(wptr + k0 + 32);
            rw1 = *(const bf16x8*)(wptr + k0 + 40);
        }
        __syncthreads();

        bf16x8 af[4], bfg[4];
        const int kc = lg * 8;
        #pragma unroll
        for (int mi = 0; mi < 4; ++mi)
            af[mi] = *(const bf16x8*)&As[wm + mi * 16 + l16][kc];
        #pragma unroll
        for (int ni = 0; ni < 4; ++ni)
            bfg[ni] = *(const bf16x8*)&Bs[wn + ni * 16 + l16][kc];
        #pragma unroll
        for (int mi = 0; mi < 4; ++mi)
            #pragma unroll
            for (int ni = 0; ni < 4; ++ni)
                acc[mi][ni] = __builtin_amdgcn_mfma_f32_16x16x32_bf16(
                    af[mi], bfg[ni], acc[mi][ni], 0, 0, 0);
        __syncthreads();
    }

    #pragma unroll
    for (int mi = 0; mi < 4; ++mi) {
        const int row = m0 + wm + mi * 16 + lg * 4;
        const int bb = row / SEQ;
        #pragma unroll
        for (int ni = 0; ni < 4; ++ni) {
            const int col = n0 + wn + ni * 16 + l16;
            const float bv = bias[col];
            const int hh = col >> 6, dd = col & 63;
            #pragma unroll
            for (int j = 0; j < 4; ++j) {
                float val = acc[mi][ni][j] + bv;
                if (sub == 0) {
                    Qp[(long)(row + j) * DIM + col] = f2bf(val * 0.125f);
                } else {
                    const int tok = (row % SEQ) + j;
                    const long pbase = (long)(bb * NHEAD + hh) * 65536;
                    if (sub == 1)
                        Kp[pbase + kfrag_addr(tok, dd)] = f2bf(val);
                    else
                        Vp[pbase + vfrag_addr(tok, dd)] = f2bf(val);
                }
            }
        }
    }
}

// Output projection: C fp32 = A(bf16) @ W^T + bias
__global__ __launch_bounds__(256, 4)
void gemm_out(const short* __restrict__ A, const short* __restrict__ W,
              const float* __restrict__ bias, float* __restrict__ Cout) {
    constexpr int K  = DIM;
    constexpr int NT = DIM / 128;
    __shared__ short As[128][72];
    __shared__ short Bs[128][72];

    const int bm = blockIdx.x / NT, bn = blockIdx.x % NT;
    const int m0 = bm * 128, n0 = bn * 128;
    const int t = threadIdx.x;
    const int lane = t & 63, w = t >> 6;
    const int wm = (w >> 1) * 64, wn = (w & 1) * 64;
    const int l16 = lane & 15, lg = lane >> 4;

    const int sr = t >> 1, sc = (t & 1) * 16;
    const short* aptr = A + (long)(m0 + sr) * K + sc;
    const short* wptr = W + (long)(n0 + sr) * K + sc;

    bf16x8 ra0 = *(const bf16x8*)(aptr);
    bf16x8 ra1 = *(const bf16x8*)(aptr + 8);
    bf16x8 rw0 = *(const bf16x8*)(wptr);
    bf16x8 rw1 = *(const bf16x8*)(wptr + 8);

    f32x4 acc[4][4] = {};

    for (int k0 = 0; k0 < K; k0 += 32) {
        *(bf16x8*)&As[sr][sc]     = ra0;
        *(bf16x8*)&As[sr][sc + 8] = ra1;
        *(bf16x8*)&Bs[sr][sc]     = rw0;
        *(bf16x8*)&Bs[sr][sc + 8] = rw1;
        if (k0 + 32 < K) {
            ra0 = *(const bf16x8*)(aptr + k0 + 32);
            ra1 = *(const bf16x8*)(aptr + k0 + 40);
            rw0 = *(const bf16x8*)(wptr + k0 + 32);
            rw1 = *(const bf16x8*)(wptr + k0 + 40);
        }
        __syncthreads();

        bf16x8 af[4], bfg[4];
        const int kc = lg * 8;
        #pragma unroll
        for (int mi = 0; mi < 4; ++mi)
            af[mi] = *(const bf16x8*)&As[wm + mi * 16 + l16][kc];
        #pragma unroll
        for (int ni = 0; ni < 4; ++ni)
            bfg[ni] = *(const bf16x8*)&Bs[wn + ni * 16 + l16][kc];
        #pragma unroll
        for (int mi = 0; mi < 4; ++mi)
            #pragma unroll
            for (int ni = 0; ni < 4; ++ni)
                acc[mi][ni] = __builtin_amdgcn_mfma_f32_16x16x32_bf16(
                    af[mi], bfg[ni], acc[mi][ni], 0, 0, 0);
        __syncthreads();
    }

    #pragma unroll
    for (int mi = 0; mi < 4; ++mi) {
        const int row = m0 + wm + mi * 16 + lg * 4;
        #pragma unroll
        for (int ni = 0; ni < 4; ++ni) {
            const int col = n0 + wn + ni * 16 + l16;
            const float bv = bias[col];
            #pragma unroll
            for (int j = 0; j < 4; ++j)
                Cout[(long)(row + j) * DIM + col] = acc[mi][ni][j] + bv;
        }
    }
}

// Flash attention. Double-buffered masked-bias LDS (1 barrier/tile), P aliased
// into CUR buffer rows, K register-prefetched one tile ahead (crosses the
// barrier in regs), V direct (compiler hoists above softmax, no barrier between).
__global__ __launch_bounds__(256, 4)
void attn_kernel(const short* __restrict__ Qp, const short* __restrict__ Kt,
                 const short* __restrict__ Vt, const float* __restrict__ bias,
                 const int* __restrict__ mask, short* __restrict__ Op) {
    __shared__ float Bsm[2][64][68];   // 34.8 KB

    const int d = blockIdx.x;
    const int lgc = (d & 7) * 192 + (d >> 3);   // XCD-contiguous (b,h) pairs
    const int qt = lgc & 15, pair = lgc >> 4;
    const int h = pair % NHEAD, b = pair / NHEAD;

    const int t = threadIdx.x, lane = t & 63, w = t >> 6;
    const int l16 = lane & 15, lg = lane >> 4;
    const int ql = w * 16 + l16;

    const int qrow = qt * 64 + ql;
    const short* qptr = Qp + (long)(b * SEQ + qrow) * DIM + h * HDIM + lg * 8;
    const bf16x8 qf0 = *(const bf16x8*)qptr;
    const bf16x8 qf1 = *(const bf16x8*)(qptr + 32);

    const short* ktile = Kt + (long)pair * 65536 + lane * 8;
    const short* vtile = Vt + (long)pair * 65536 + lane * 8;

    const int srow = t >> 4, scol = (t & 15) * 4;
    const float* bst = bias + ((long)pair * SEQ + qt * 64 + srow) * SEQ + scol;
    const int*   mst = mask + ((long)b * SEQ + qt * 64 + srow) * SEQ + scol;

    f32x4 acc_o[4] = {};
    float m_run = -1e30f, l_run = 0.f;
    constexpr float L2E = 1.4426950408889634f;

    f32x4 br[4]; i32x4 mr[4];
    bf16x8 kpre[8];                    // next-tile K fragments (32 VGPR)

    auto issue_bm = [&](int kt) {
        #pragma unroll
        for (int i = 0; i < 4; ++i) {
            br[i] = __builtin_nontemporal_load((const f32x4*)(bst + (long)i * 16 * SEQ + kt * 64));
            mr[i] = *(const i32x4*)(mst + (long)i * 16 * SEQ + kt * 64);
        }
    };
    auto write_bm = [&](int buf) {
        #pragma unroll
        for (int i = 0; i < 4; ++i) {
            f32x4 o;
            #pragma unroll
            for (int j = 0; j < 4; ++j) o[j] = mr[i][j] ? br[i][j] : -1e30f;
            *(f32x4*)&Bsm[buf][i * 16 + srow][scol] = o;
        }
    };
    auto issue_k = [&](int kt) {
        const short* kf = ktile + kt * 4096;
        #pragma unroll
        for (int c = 0; c < 4; ++c) {
            kpre[c]     = *(const bf16x8*)(kf + c * 1024);
            kpre[4 + c] = *(const bf16x8*)(kf + c * 1024 + 512);
        }
    };

    auto compute = [&](int kt, int buf) {
        const short* vf = vtile + kt * 4096;
        short* prow = (short*)&Bsm[buf][ql][0];   // wave-private row in CUR buffer

        // QK^T from prefetched K regs (loaded a full iteration ago)
        f32x4 s[4];
        __builtin_amdgcn_s_setprio(1);
        #pragma unroll
        for (int c = 0; c < 4; ++c) {
            f32x4 ci = *(const f32x4*)&Bsm[buf][ql][c * 16 + lg * 4];
            s[c] = __builtin_amdgcn_mfma_f32_16x16x32_bf16(kpre[c], qf0, ci, 0, 0, 0);
        }
        #pragma unroll
        for (int c = 0; c < 4; ++c)
            s[c] = __builtin_amdgcn_mfma_f32_16x16x32_bf16(kpre[4 + c], qf1, s[c], 0, 0, 0);
        __builtin_amdgcn_s_setprio(0);

        // re-issue K for next tile (covered by softmax + PV + barrier)
        if (kt < 15) issue_k(kt + 1);

        float mt = -1e30f;
        #pragma unroll
        for (int c = 0; c < 4; ++c)
            #pragma unroll
            for (int j = 0; j < 4; ++j)
                mt = fmaxf(mt, s[c][j]);
        mt = fmaxf(mt, __shfl_xor(mt, 16));
        mt = fmaxf(mt, __shfl_xor(mt, 32));
        const float mn = fmaxf(m_run, mt);
        const float alpha = fexp2((m_run - mn) * L2E);
        m_run = mn;
        const float nm = -mn * L2E;

        float lt = 0.f;
        #pragma unroll
        for (int c = 0; c < 4; ++c) {
            bf16x4 pk;
            #pragma unroll
            for (int j = 0; j < 4; ++j) {
                const float e = fexp2(fmaf(s[c][j], L2E, nm));
                lt += e;
                pk[j] = f2bf(e);
            }
            *(bf16x4*)(prow + c * 16 + lg * 4) = pk;
        }
        lt += __shfl_xor(lt, 16);
        lt += __shfl_xor(lt, 32);
        l_run = l_run * alpha + lt;

        float al[4];
        #pragma unroll
        for (int j = 0; j < 4; ++j) al[j] = __shfl(alpha, lg * 4 + j);
        #pragma unroll
        for (int df = 0; df < 4; ++df)
            #pragma unroll
            for (int j = 0; j < 4; ++j)
                acc_o[df][j] *= al[j];

        const bf16x8 pa0 = *(const bf16x8*)(prow + lg * 8);
        const bf16x8 pa1 = *(const bf16x8*)(prow + 32 + lg * 8);
        __builtin_amdgcn_s_setprio(1);
        #pragma unroll
        for (int df = 0; df < 4; ++df) {
            const bf16x8 vb = *(const bf16x8*)(vf + df * 1024);
            acc_o[df] = __builtin_amdgcn_mfma_f32_16x16x32_bf16(pa0, vb, acc_o[df], 0, 0, 0);
        }
        #pragma unroll
        for (int df = 0; df < 4; ++df) {
            const bf16x8 vb = *(const bf16x8*)(vf + df * 1024 + 512);
            acc_o[df] = __builtin_amdgcn_mfma_f32_16x16x32_bf16(pa1, vb, acc_o[df], 0, 0, 0);
        }
        __builtin_amdgcn_s_setprio(0);
    };

    // prologue: tile 0 into buf0; tile-1 bias loads + tile-0 K in flight
    issue_bm(0);
    write_bm(0);
    issue_bm(1);
    issue_k(0);
    __syncthreads();

    int cur = 0;
    for (int kt = 0; kt < 16; ++kt) {
        compute(kt, cur);
        if (kt < 15) {
            write_bm(cur ^ 1);              // regs for kt+1 (issued a full iter ago)
            if (kt < 14) issue_bm(kt + 2);  // next-next: full-iter + barrier cover
            __syncthreads();
            cur ^= 1;
        }
    }

    float linv[4];
    #pragma unroll
    for (int j = 0; j < 4; ++j)
        linv[j] = 1.f / fmaxf(__shfl(l_run, lg * 4 + j), 1e-20f);

    #pragma unroll
    for (int df = 0; df < 4; ++df) {
        #pragma unroll
        for (int j = 0; j < 4; ++j) {
            const float val = acc_o[df][j] * linv[j];
            const int row = b * SEQ + qt * 64 + w * 16 + lg * 4 + j;
            const int col = h * HDIM + df * 16 + l16;
            Op[(long)row * DIM + col] = f2bf(val);
        }
    }
}

extern "C" void kernel_launch(void* const* d_in, const int* in_sizes, int n_in,
                              void* d_out, int out_size, void* d_ws, size_t ws_size,
                              hipStream_t stream) {
    const float* q         = (const float*)d_in[0];
    const float* k         = (const float*)d_in[1];
    const float* v         = (const float*)d_in[2];
    const float* attn_bias = (const float*)d_in[3];
    const int*   attn_mask = (const int*)d_in[4];
    const float* Wq = (const float*)d_in[5];
    const float* bq = (const float*)d_in[6];
    const float* Wk = (const float*)d_in[7];
    const float* bk = (const float*)d_in[8];
    const float* Wv = (const float*)d_in[9];
    const float* bv = (const float*)d_in[10];
    const float* Wo = (const float*)d_in[11];
    const float* bo = (const float*)d_in[12];
    float* out = (float*)d_out;

    const long NED = (long)MROWS * DIM;       // 6291456
    const long WED = (long)DIM * DIM;         // 589824
    short* Qp  = (short*)d_ws;                // [8192][768] bf16, pre-scaled 1/8
    short* Kp  = Qp + NED;                    // K fragment-order [96][16][4096]
    short* Vp  = Kp + NED;                    // V fragment-order [96][16][4096]
    short* Op  = Vp + NED;
    short* Wqb = Op + NED;                    // bf16 weights
    short* Wkb = Wqb + WED;
    short* Wvb = Wkb + WED;
    short* Wob = Wvb + WED;

    const dim3 blk(256);

    cvt_w<<<288, blk, 0, stream>>>(Wq, Wk, Wv, Wo, Wqb, Wkb, Wvb, Wob, (int)(WED / 8));

    const int gemm_grid = (MROWS / 128) * (DIM / 128);   // 384
    gemm_qkv<<<3 * gemm_grid, blk, 0, stream>>>(q, k, v, Wqb, Wkb, Wvb,
                                                bq, bk, bv, Qp, Kp, Vp);

    const int attn_grid = BATCH * NHEAD * (SEQ / 64);    // 1536
    attn_kernel<<<attn_grid, blk, 0, stream>>>(Qp, Kp, Vp, attn_bias, attn_mask, Op);

    gemm_out<<<gemm_grid, blk, 0, stream>>>(Op, Wob, bo, out);
}

// Round 11
// 268.375 us; speedup vs baseline: 1.1219x; 1.1219x over previous
//
#include <hip/hip_runtime.h>
#include <hip/hip_bf16.h>

using f32x4  = __attribute__((ext_vector_type(4))) float;
using i32x4  = __attribute__((ext_vector_type(4))) int;
using bf16x8 = __attribute__((ext_vector_type(8))) short;
using bf16x4 = __attribute__((ext_vector_type(4))) short;

constexpr int BATCH = 8, SEQ = 1024, DIM = 768, NHEAD = 12, HDIM = 64;
constexpr int MROWS = BATCH * SEQ;   // 8192

__device__ __forceinline__ short f2bf(float f) {
    union { float f; unsigned u; } x; x.f = f;
    unsigned r = (x.u + 0x7fffu + ((x.u >> 16) & 1u)) >> 16;
    return (short)r;
}
__device__ __forceinline__ float fexp2(float x) { return __builtin_amdgcn_exp2f(x); }

__device__ __forceinline__ bf16x8 cvt8(const float* p) {
    const f32x4 x0 = *(const f32x4*)p;
    const f32x4 x1 = *(const f32x4*)(p + 4);
    bf16x8 r;
    #pragma unroll
    for (int j = 0; j < 4; ++j) { r[j] = f2bf(x0[j]); r[4 + j] = f2bf(x1[j]); }
    return r;
}

// K fragment-order: attn reads kb[c][ks] at kt*4096 + c*1024 + ks*512 + lane*8
// (l16 = key&15, lg = hd-slot). Element (tok, dd):
__device__ __forceinline__ long kfrag_addr(int tok, int dd) {
    return ((long)(tok >> 6)) * 4096 + ((tok & 63) >> 4) * 1024 + (dd >> 5) * 512
         + ((dd >> 3) & 3) * 128 + (tok & 15) * 8 + (dd & 7);
}
// V fragment-order: attn reads vb[df][ks] at kt*4096 + df*1024 + ks*512 + lane*8
// (l16 = hd&15, lg = key-slot). Element (tok, dd):
__device__ __forceinline__ long vfrag_addr(int tok, int dd) {
    return ((long)(tok >> 6)) * 4096 + (dd >> 4) * 1024 + ((tok >> 5) & 1) * 512
         + ((tok >> 3) & 3) * 128 + (dd & 15) * 8 + (tok & 7);
}

// weights-only bf16 prepass (tiny, L2-hot panels reused 64x by gemm blocks)
__global__ __launch_bounds__(256)
void cvt_w(const float* __restrict__ Wq, const float* __restrict__ Wk,
           const float* __restrict__ Wv, const float* __restrict__ Wo,
           short* __restrict__ Wqb, short* __restrict__ Wkb,
           short* __restrict__ Wvb, short* __restrict__ Wob, int n8) {
    const int stride = gridDim.x * 256;
    for (int i = blockIdx.x * 256 + threadIdx.x; i < n8; i += stride) {
        const long base = (long)i * 8;
        *(bf16x8*)(Wqb + base) = cvt8(Wq + base);
        *(bf16x8*)(Wkb + base) = cvt8(Wk + base);
        *(bf16x8*)(Wvb + base) = cvt8(Wv + base);
        *(bf16x8*)(Wob + base) = cvt8(Wo + base);
    }
}

// Fused Q/K/V projection, A staged DIRECTLY from fp32 (T14: issue-early,
// cvt+write-late), W from bf16. sub = bid%3 interleave for co-residency.
__global__ __launch_bounds__(256, 4)
void gemm_qkv(const float* __restrict__ qf, const float* __restrict__ kf,
              const float* __restrict__ vf,
              const short* __restrict__ Wqb, const short* __restrict__ Wkb,
              const short* __restrict__ Wvb,
              const float* __restrict__ bq, const float* __restrict__ bk,
              const float* __restrict__ bv,
              short* __restrict__ Qp, short* __restrict__ Kp, short* __restrict__ Vp) {
    constexpr int K  = DIM;
    constexpr int NT = DIM / 128;
    __shared__ short As[128][72];
    __shared__ short Bs[128][72];

    const int sub = blockIdx.x % 3;
    const int bid = blockIdx.x / 3;
    const float* A = sub == 0 ? qf : sub == 1 ? kf : vf;
    const short* W = sub == 0 ? Wqb : sub == 1 ? Wkb : Wvb;
    const float* bias = sub == 0 ? bq : sub == 1 ? bk : bv;

    const int bm = bid / NT, bn = bid % NT;
    const int m0 = bm * 128, n0 = bn * 128;
    const int t = threadIdx.x;
    const int lane = t & 63, w = t >> 6;
    const int wm = (w >> 1) * 64, wn = (w & 1) * 64;
    const int l16 = lane & 15, lg = lane >> 4;

    const int sr = t >> 1, sc = (t & 1) * 16;
    const float* aptr = A + (long)(m0 + sr) * K + sc;
    const short* wptr = W + (long)(n0 + sr) * K + sc;

    f32x4 ra[4];
    #pragma unroll
    for (int i = 0; i < 4; ++i) ra[i] = *(const f32x4*)(aptr + i * 4);
    bf16x8 rw0 = *(const bf16x8*)(wptr);
    bf16x8 rw1 = *(const bf16x8*)(wptr + 8);

    f32x4 acc[4][4] = {};

    for (int k0 = 0; k0 < K; k0 += 32) {
        short tb[16];
        #pragma unroll
        for (int i = 0; i < 4; ++i)
            #pragma unroll
            for (int j = 0; j < 4; ++j) tb[i * 4 + j] = f2bf(ra[i][j]);
        *(bf16x8*)&As[sr][sc]     = *(bf16x8*)&tb[0];
        *(bf16x8*)&As[sr][sc + 8] = *(bf16x8*)&tb[8];
        *(bf16x8*)&Bs[sr][sc]     = rw0;
        *(bf16x8*)&Bs[sr][sc + 8] = rw1;
        if (k0 + 32 < K) {
            #pragma unroll
            for (int i = 0; i < 4; ++i) ra[i] = *(const f32x4*)(aptr + k0 + 32 + i * 4);
            rw0 = *(const bf16x8*)(wptr + k0 + 32);
            rw1 = *(const bf16x8*)(wptr + k0 + 40);
        }
        __syncthreads();

        bf16x8 af[4], bfg[4];
        const int kc = lg * 8;
        #pragma unroll
        for (int mi = 0; mi < 4; ++mi)
            af[mi] = *(const bf16x8*)&As[wm + mi * 16 + l16][kc];
        #pragma unroll
        for (int ni = 0; ni < 4; ++ni)
            bfg[ni] = *(const bf16x8*)&Bs[wn + ni * 16 + l16][kc];
        #pragma unroll
        for (int mi = 0; mi < 4; ++mi)
            #pragma unroll
            for (int ni = 0; ni < 4; ++ni)
                acc[mi][ni] = __builtin_amdgcn_mfma_f32_16x16x32_bf16(
                    af[mi], bfg[ni], acc[mi][ni], 0, 0, 0);
        __syncthreads();
    }

    #pragma unroll
    for (int mi = 0; mi < 4; ++mi) {
        const int row = m0 + wm + mi * 16 + lg * 4;
        const int bb = row / SEQ;
        #pragma unroll
        for (int ni = 0; ni < 4; ++ni) {
            const int col = n0 + wn + ni * 16 + l16;
            const float bv = bias[col];
            const int hh = col >> 6, dd = col & 63;
            #pragma unroll
            for (int j = 0; j < 4; ++j) {
                float val = acc[mi][ni][j] + bv;
                if (sub == 0) {
                    Qp[(long)(row + j) * DIM + col] = f2bf(val * 0.125f);
                } else {
                    const int tok = (row % SEQ) + j;
                    const long pbase = (long)(bb * NHEAD + hh) * 65536;
                    if (sub == 1)
                        Kp[pbase + kfrag_addr(tok, dd)] = f2bf(val);
                    else
                        Vp[pbase + vfrag_addr(tok, dd)] = f2bf(val);
                }
            }
        }
    }
}

// Output projection: C fp32 = A(bf16) @ W^T + bias
__global__ __launch_bounds__(256, 4)
void gemm_out(const short* __restrict__ A, const short* __restrict__ W,
              const float* __restrict__ bias, float* __restrict__ Cout) {
    constexpr int K  = DIM;
    constexpr int NT = DIM / 128;
    __shared__ short As[128][72];
    __shared__ short Bs[128][72];

    const int bm = blockIdx.x / NT, bn = blockIdx.x % NT;
    const int m0 = bm * 128, n0 = bn * 128;
    const int t = threadIdx.x;
    const int lane = t & 63, w = t >> 6;
    const int wm = (w >> 1) * 64, wn = (w & 1) * 64;
    const int l16 = lane & 15, lg = lane >> 4;

    const int sr = t >> 1, sc = (t & 1) * 16;
    const short* aptr = A + (long)(m0 + sr) * K + sc;
    const short* wptr = W + (long)(n0 + sr) * K + sc;

    bf16x8 ra0 = *(const bf16x8*)(aptr);
    bf16x8 ra1 = *(const bf16x8*)(aptr + 8);
    bf16x8 rw0 = *(const bf16x8*)(wptr);
    bf16x8 rw1 = *(const bf16x8*)(wptr + 8);

    f32x4 acc[4][4] = {};

    for (int k0 = 0; k0 < K; k0 += 32) {
        *(bf16x8*)&As[sr][sc]     = ra0;
        *(bf16x8*)&As[sr][sc + 8] = ra1;
        *(bf16x8*)&Bs[sr][sc]     = rw0;
        *(bf16x8*)&Bs[sr][sc + 8] = rw1;
        if (k0 + 32 < K) {
            ra0 = *(const bf16x8*)(aptr + k0 + 32);
            ra1 = *(const bf16x8*)(aptr + k0 + 40);
            rw0 = *(const bf16x8*)(wptr + k0 + 32);
            rw1 = *(const bf16x8*)(wptr + k0 + 40);
        }
        __syncthreads();

        bf16x8 af[4], bfg[4];
        const int kc = lg * 8;
        #pragma unroll
        for (int mi = 0; mi < 4; ++mi)
            af[mi] = *(const bf16x8*)&As[wm + mi * 16 + l16][kc];
        #pragma unroll
        for (int ni = 0; ni < 4; ++ni)
            bfg[ni] = *(const bf16x8*)&Bs[wn + ni * 16 + l16][kc];
        #pragma unroll
        for (int mi = 0; mi < 4; ++mi)
            #pragma unroll
            for (int ni = 0; ni < 4; ++ni)
                acc[mi][ni] = __builtin_amdgcn_mfma_f32_16x16x32_bf16(
                    af[mi], bfg[ni], acc[mi][ni], 0, 0, 0);
        __syncthreads();
    }

    #pragma unroll
    for (int mi = 0; mi < 4; ++mi) {
        const int row = m0 + wm + mi * 16 + lg * 4;
        #pragma unroll
        for (int ni = 0; ni < 4; ++ni) {
            const int col = n0 + wn + ni * 16 + l16;
            const float bv = bias[col];
            #pragma unroll
            for (int j = 0; j < 4; ++j)
                Cout[(long)(row + j) * DIM + col] = acc[mi][ni][j] + bv;
        }
    }
}

// Flash attention (round-9 version: direct K/V loads, no K reg-prefetch).
// Double-buffered masked-bias LDS (1 barrier/tile), P aliased into CUR rows.
__global__ __launch_bounds__(256, 4)
void attn_kernel(const short* __restrict__ Qp, const short* __restrict__ Kt,
                 const short* __restrict__ Vt, const float* __restrict__ bias,
                 const int* __restrict__ mask, short* __restrict__ Op) {
    __shared__ float Bsm[2][64][68];   // 34.8 KB

    const int d = blockIdx.x;
    const int lgc = (d & 7) * 192 + (d >> 3);   // XCD-contiguous (b,h) pairs
    const int qt = lgc & 15, pair = lgc >> 4;
    const int h = pair % NHEAD, b = pair / NHEAD;

    const int t = threadIdx.x, lane = t & 63, w = t >> 6;
    const int l16 = lane & 15, lg = lane >> 4;
    const int ql = w * 16 + l16;

    const int qrow = qt * 64 + ql;
    const short* qptr = Qp + (long)(b * SEQ + qrow) * DIM + h * HDIM + lg * 8;
    const bf16x8 qf0 = *(const bf16x8*)qptr;
    const bf16x8 qf1 = *(const bf16x8*)(qptr + 32);

    const short* ktile = Kt + (long)pair * 65536 + lane * 8;
    const short* vtile = Vt + (long)pair * 65536 + lane * 8;

    const int srow = t >> 4, scol = (t & 15) * 4;
    const float* bst = bias + ((long)pair * SEQ + qt * 64 + srow) * SEQ + scol;
    const int*   mst = mask + ((long)b * SEQ + qt * 64 + srow) * SEQ + scol;

    f32x4 acc_o[4] = {};
    float m_run = -1e30f, l_run = 0.f;
    constexpr float L2E = 1.4426950408889634f;

    f32x4 br[4]; i32x4 mr[4];

    auto issue_bm = [&](int kt) {
        #pragma unroll
        for (int i = 0; i < 4; ++i) {
            br[i] = __builtin_nontemporal_load((const f32x4*)(bst + (long)i * 16 * SEQ + kt * 64));
            mr[i] = *(const i32x4*)(mst + (long)i * 16 * SEQ + kt * 64);
        }
    };
    auto write_bm = [&](int buf) {
        #pragma unroll
        for (int i = 0; i < 4; ++i) {
            f32x4 o;
            #pragma unroll
            for (int j = 0; j < 4; ++j) o[j] = mr[i][j] ? br[i][j] : -1e30f;
            *(f32x4*)&Bsm[buf][i * 16 + srow][scol] = o;
        }
    };

    auto compute = [&](int kt, int buf) {
        const short* kf = ktile + kt * 4096;
        const short* vf = vtile + kt * 4096;
        short* prow = (short*)&Bsm[buf][ql][0];   // wave-private row in CUR buffer

        f32x4 s[4];
        __builtin_amdgcn_s_setprio(1);
        #pragma unroll
        for (int c = 0; c < 4; ++c) {
            const bf16x8 kb = *(const bf16x8*)(kf + c * 1024);
            f32x4 ci = *(const f32x4*)&Bsm[buf][ql][c * 16 + lg * 4];
            s[c] = __builtin_amdgcn_mfma_f32_16x16x32_bf16(kb, qf0, ci, 0, 0, 0);
        }
        #pragma unroll
        for (int c = 0; c < 4; ++c) {
            const bf16x8 kb = *(const bf16x8*)(kf + c * 1024 + 512);
            s[c] = __builtin_amdgcn_mfma_f32_16x16x32_bf16(kb, qf1, s[c], 0, 0, 0);
        }
        __builtin_amdgcn_s_setprio(0);

        float mt = -1e30f;
        #pragma unroll
        for (int c = 0; c < 4; ++c)
            #pragma unroll
            for (int j = 0; j < 4; ++j)
                mt = fmaxf(mt, s[c][j]);
        mt = fmaxf(mt, __shfl_xor(mt, 16));
        mt = fmaxf(mt, __shfl_xor(mt, 32));
        const float mn = fmaxf(m_run, mt);
        const float alpha = fexp2((m_run - mn) * L2E);
        m_run = mn;
        const float nm = -mn * L2E;

        float lt = 0.f;
        #pragma unroll
        for (int c = 0; c < 4; ++c) {
            bf16x4 pk;
            #pragma unroll
            for (int j = 0; j < 4; ++j) {
                const float e = fexp2(fmaf(s[c][j], L2E, nm));
                lt += e;
                pk[j] = f2bf(e);
            }
            *(bf16x4*)(prow + c * 16 + lg * 4) = pk;
        }
        lt += __shfl_xor(lt, 16);
        lt += __shfl_xor(lt, 32);
        l_run = l_run * alpha + lt;

        float al[4];
        #pragma unroll
        for (int j = 0; j < 4; ++j) al[j] = __shfl(alpha, lg * 4 + j);
        #pragma unroll
        for (int df = 0; df < 4; ++df)
            #pragma unroll
            for (int j = 0; j < 4; ++j)
                acc_o[df][j] *= al[j];

        const bf16x8 pa0 = *(const bf16x8*)(prow + lg * 8);
        const bf16x8 pa1 = *(const bf16x8*)(prow + 32 + lg * 8);
        __builtin_amdgcn_s_setprio(1);
        #pragma unroll
        for (int df = 0; df < 4; ++df) {
            const bf16x8 vb = *(const bf16x8*)(vf + df * 1024);
            acc_o[df] = __builtin_amdgcn_mfma_f32_16x16x32_bf16(pa0, vb, acc_o[df], 0, 0, 0);
        }
        #pragma unroll
        for (int df = 0; df < 4; ++df) {
            const bf16x8 vb = *(const bf16x8*)(vf + df * 1024 + 512);
            acc_o[df] = __builtin_amdgcn_mfma_f32_16x16x32_bf16(pa1, vb, acc_o[df], 0, 0, 0);
        }
        __builtin_amdgcn_s_setprio(0);
    };

    // prologue: tile 0 into buf0; tile 1 loads in flight
    issue_bm(0);
    write_bm(0);
    issue_bm(1);
    __syncthreads();

    int cur = 0;
    for (int kt = 0; kt < 16; ++kt) {
        compute(kt, cur);
        if (kt < 15) {
            write_bm(cur ^ 1);              // regs for kt+1 (issued a full iter ago)
            if (kt < 14) issue_bm(kt + 2);  // next-next: full-iter + barrier cover
            __syncthreads();
            cur ^= 1;
        }
    }

    float linv[4];
    #pragma unroll
    for (int j = 0; j < 4; ++j)
        linv[j] = 1.f / fmaxf(__shfl(l_run, lg * 4 + j), 1e-20f);

    #pragma unroll
    for (int df = 0; df < 4; ++df) {
        #pragma unroll
        for (int j = 0; j < 4; ++j) {
            const float val = acc_o[df][j] * linv[j];
            const int row = b * SEQ + qt * 64 + w * 16 + lg * 4 + j;
            const int col = h * HDIM + df * 16 + l16;
            Op[(long)row * DIM + col] = f2bf(val);
        }
    }
}

extern "C" void kernel_launch(void* const* d_in, const int* in_sizes, int n_in,
                              void* d_out, int out_size, void* d_ws, size_t ws_size,
                              hipStream_t stream) {
    const float* q         = (const float*)d_in[0];
    const float* k         = (const float*)d_in[1];
    const float* v         = (const float*)d_in[2];
    const float* attn_bias = (const float*)d_in[3];
    const int*   attn_mask = (const int*)d_in[4];
    const float* Wq = (const float*)d_in[5];
    const float* bq = (const float*)d_in[6];
    const float* Wk = (const float*)d_in[7];
    const float* bk = (const float*)d_in[8];
    const float* Wv = (const float*)d_in[9];
    const float* bv = (const float*)d_in[10];
    const float* Wo = (const float*)d_in[11];
    const float* bo = (const float*)d_in[12];
    float* out = (float*)d_out;

    const long NED = (long)MROWS * DIM;       // 6291456
    const long WED = (long)DIM * DIM;         // 589824
    short* Qp  = (short*)d_ws;                // [8192][768] bf16, pre-scaled 1/8
    short* Kp  = Qp + NED;                    // K fragment-order [96][16][4096]
    short* Vp  = Kp + NED;                    // V fragment-order [96][16][4096]
    short* Op  = Vp + NED;
    short* Wqb = Op + NED;                    // bf16 weights
    short* Wkb = Wqb + WED;
    short* Wvb = Wkb + WED;
    short* Wob = Wvb + WED;

    const dim3 blk(256);

    cvt_w<<<288, blk, 0, stream>>>(Wq, Wk, Wv, Wo, Wqb, Wkb, Wvb, Wob, (int)(WED / 8));

    const int gemm_grid = (MROWS / 128) * (DIM / 128);   // 384
    gemm_qkv<<<3 * gemm_grid, blk, 0, stream>>>(q, k, v, Wqb, Wkb, Wvb,
                                                bq, bk, bv, Qp, Kp, Vp);

    const int attn_grid = BATCH * NHEAD * (SEQ / 64);    // 1536
    attn_kernel<<<attn_grid, blk, 0, stream>>>(Qp, Kp, Vp, attn_bias, attn_mask, Op);

    gemm_out<<<gemm_grid, blk, 0, stream>>>(Op, Wob, bo, out);
}

// Round 12
// 257.313 us; speedup vs baseline: 1.1702x; 1.0430x over previous
//
#include <hip/hip_runtime.h>
#include <hip/hip_bf16.h>

using f32x4  = __attribute__((ext_vector_type(4))) float;
using i32x4  = __attribute__((ext_vector_type(4))) int;
using bf16x8 = __attribute__((ext_vector_type(8))) short;
using bf16x4 = __attribute__((ext_vector_type(4))) short;

constexpr int BATCH = 8, SEQ = 1024, DIM = 768, NHEAD = 12, HDIM = 64;
constexpr int MROWS = BATCH * SEQ;   // 8192

__device__ __forceinline__ short f2bf(float f) {
    union { float f; unsigned u; } x; x.f = f;
    unsigned r = (x.u + 0x7fffu + ((x.u >> 16) & 1u)) >> 16;
    return (short)r;
}
__device__ __forceinline__ float fexp2(float x) { return __builtin_amdgcn_exp2f(x); }

__device__ __forceinline__ bf16x8 cvt8(const float* p) {
    const f32x4 x0 = *(const f32x4*)p;
    const f32x4 x1 = *(const f32x4*)(p + 4);
    bf16x8 r;
    #pragma unroll
    for (int j = 0; j < 4; ++j) { r[j] = f2bf(x0[j]); r[4 + j] = f2bf(x1[j]); }
    return r;
}

// K fragment-order: attn reads kb[c][ks] at kt*4096 + c*1024 + ks*512 + lane*8
// (l16 = key&15, lg = hd-slot). Element (tok, dd):
__device__ __forceinline__ long kfrag_addr(int tok, int dd) {
    return ((long)(tok >> 6)) * 4096 + ((tok & 63) >> 4) * 1024 + (dd >> 5) * 512
         + ((dd >> 3) & 3) * 128 + (tok & 15) * 8 + (dd & 7);
}
// V fragment-order: attn reads vb[df][ks] at kt*4096 + df*1024 + ks*512 + lane*8
// (l16 = hd&15, lg = key-slot). Element (tok, dd):
__device__ __forceinline__ long vfrag_addr(int tok, int dd) {
    return ((long)(tok >> 6)) * 4096 + (dd >> 4) * 1024 + ((tok >> 5) & 1) * 512
         + ((tok >> 3) & 3) * 128 + (dd & 15) * 8 + (tok & 7);
}

// single fp32->bf16 prepass: 3 big arrays + 4 weight arrays in one launch
__global__ __launch_bounds__(256)
void cvt_all(const float* __restrict__ q, const float* __restrict__ k,
             const float* __restrict__ v,
             const float* __restrict__ Wq, const float* __restrict__ Wk,
             const float* __restrict__ Wv, const float* __restrict__ Wo,
             short* __restrict__ qb, short* __restrict__ kb, short* __restrict__ vb,
             short* __restrict__ Wqb, short* __restrict__ Wkb,
             short* __restrict__ Wvb, short* __restrict__ Wob,
             int nbig8, int nsml8) {
    const int stride = gridDim.x * 256;
    for (int i = blockIdx.x * 256 + threadIdx.x; i < nbig8; i += stride) {
        const long base = (long)i * 8;
        *(bf16x8*)(qb + base) = cvt8(q + base);
        *(bf16x8*)(kb + base) = cvt8(k + base);
        *(bf16x8*)(vb + base) = cvt8(v + base);
    }
    for (int i = blockIdx.x * 256 + threadIdx.x; i < nsml8; i += stride) {
        const long base = (long)i * 8;
        *(bf16x8*)(Wqb + base) = cvt8(Wq + base);
        *(bf16x8*)(Wkb + base) = cvt8(Wk + base);
        *(bf16x8*)(Wvb + base) = cvt8(Wv + base);
        *(bf16x8*)(Wob + base) = cvt8(Wo + base);
    }
}

// Fused Q/K/V projection: 3 x (M x DIM) NT-GEMMs in ONE launch, sub = bid%3.
__global__ __launch_bounds__(256, 4)
void gemm_qkv(const short* __restrict__ qb, const short* __restrict__ kb,
              const short* __restrict__ vbp,
              const short* __restrict__ Wqb, const short* __restrict__ Wkb,
              const short* __restrict__ Wvb,
              const float* __restrict__ bq, const float* __restrict__ bk,
              const float* __restrict__ bv,
              short* __restrict__ Qp, short* __restrict__ Kp, short* __restrict__ Vp) {
    constexpr int K  = DIM;
    constexpr int NT = DIM / 128;
    __shared__ short As[128][72];
    __shared__ short Bs[128][72];

    const int sub = blockIdx.x % 3;
    const int bid = blockIdx.x / 3;
    const short* A = sub == 0 ? qb : sub == 1 ? kb : vbp;
    const short* W = sub == 0 ? Wqb : sub == 1 ? Wkb : Wvb;
    const float* bias = sub == 0 ? bq : sub == 1 ? bk : bv;

    const int bm = bid / NT, bn = bid % NT;
    const int m0 = bm * 128, n0 = bn * 128;
    const int t = threadIdx.x;
    const int lane = t & 63, w = t >> 6;
    const int wm = (w >> 1) * 64, wn = (w & 1) * 64;
    const int l16 = lane & 15, lg = lane >> 4;

    const int sr = t >> 1, sc = (t & 1) * 16;
    const short* aptr = A + (long)(m0 + sr) * K + sc;
    const short* wptr = W + (long)(n0 + sr) * K + sc;

    bf16x8 ra0 = *(const bf16x8*)(aptr);
    bf16x8 ra1 = *(const bf16x8*)(aptr + 8);
    bf16x8 rw0 = *(const bf16x8*)(wptr);
    bf16x8 rw1 = *(const bf16x8*)(wptr + 8);

    f32x4 acc[4][4] = {};

    for (int k0 = 0; k0 < K; k0 += 32) {
        *(bf16x8*)&As[sr][sc]     = ra0;
        *(bf16x8*)&As[sr][sc + 8] = ra1;
        *(bf16x8*)&Bs[sr][sc]     = rw0;
        *(bf16x8*)&Bs[sr][sc + 8] = rw1;
        if (k0 + 32 < K) {
            ra0 = *(const bf16x8*)(aptr + k0 + 32);
            ra1 = *(const bf16x8*)(aptr + k0 + 40);
            rw0 = *(const bf16x8*)(wptr + k0 + 32);
            rw1 = *(const bf16x8*)(wptr + k0 + 40);
        }
        __syncthreads();

        bf16x8 af[4], bfg[4];
        const int kc = lg * 8;
        #pragma unroll
        for (int mi = 0; mi < 4; ++mi)
            af[mi] = *(const bf16x8*)&As[wm + mi * 16 + l16][kc];
        #pragma unroll
        for (int ni = 0; ni < 4; ++ni)
            bfg[ni] = *(const bf16x8*)&Bs[wn + ni * 16 + l16][kc];
        #pragma unroll
        for (int mi = 0; mi < 4; ++mi)
            #pragma unroll
            for (int ni = 0; ni < 4; ++ni)
                acc[mi][ni] = __builtin_amdgcn_mfma_f32_16x16x32_bf16(
                    af[mi], bfg[ni], acc[mi][ni], 0, 0, 0);
        __syncthreads();
    }

    #pragma unroll
    for (int mi = 0; mi < 4; ++mi) {
        const int row = m0 + wm + mi * 16 + lg * 4;
        const int bb = row / SEQ;
        #pragma unroll
        for (int ni = 0; ni < 4; ++ni) {
            const int col = n0 + wn + ni * 16 + l16;
            const float bv = bias[col];
            const int hh = col >> 6, dd = col & 63;
            #pragma unroll
            for (int j = 0; j < 4; ++j) {
                float val = acc[mi][ni][j] + bv;
                if (sub == 0) {
                    Qp[(long)(row + j) * DIM + col] = f2bf(val * 0.125f);
                } else {
                    const int tok = (row % SEQ) + j;
                    const long pbase = (long)(bb * NHEAD + hh) * 65536;
                    if (sub == 1)
                        Kp[pbase + kfrag_addr(tok, dd)] = f2bf(val);
                    else
                        Vp[pbase + vfrag_addr(tok, dd)] = f2bf(val);
                }
            }
        }
    }
}

// Output projection: C fp32 = A(bf16) @ W^T + bias
__global__ __launch_bounds__(256, 4)
void gemm_out(const short* __restrict__ A, const short* __restrict__ W,
              const float* __restrict__ bias, float* __restrict__ Cout) {
    constexpr int K  = DIM;
    constexpr int NT = DIM / 128;
    __shared__ short As[128][72];
    __shared__ short Bs[128][72];

    const int bm = blockIdx.x / NT, bn = blockIdx.x % NT;
    const int m0 = bm * 128, n0 = bn * 128;
    const int t = threadIdx.x;
    const int lane = t & 63, w = t >> 6;
    const int wm = (w >> 1) * 64, wn = (w & 1) * 64;
    const int l16 = lane & 15, lg = lane >> 4;

    const int sr = t >> 1, sc = (t & 1) * 16;
    const short* aptr = A + (long)(m0 + sr) * K + sc;
    const short* wptr = W + (long)(n0 + sr) * K + sc;

    bf16x8 ra0 = *(const bf16x8*)(aptr);
    bf16x8 ra1 = *(const bf16x8*)(aptr + 8);
    bf16x8 rw0 = *(const bf16x8*)(wptr);
    bf16x8 rw1 = *(const bf16x8*)(wptr + 8);

    f32x4 acc[4][4] = {};

    for (int k0 = 0; k0 < K; k0 += 32) {
        *(bf16x8*)&As[sr][sc]     = ra0;
        *(bf16x8*)&As[sr][sc + 8] = ra1;
        *(bf16x8*)&Bs[sr][sc]     = rw0;
        *(bf16x8*)&Bs[sr][sc + 8] = rw1;
        if (k0 + 32 < K) {
            ra0 = *(const bf16x8*)(aptr + k0 + 32);
            ra1 = *(const bf16x8*)(aptr + k0 + 40);
            rw0 = *(const bf16x8*)(wptr + k0 + 32);
            rw1 = *(const bf16x8*)(wptr + k0 + 40);
        }
        __syncthreads();

        bf16x8 af[4], bfg[4];
        const int kc = lg * 8;
        #pragma unroll
        for (int mi = 0; mi < 4; ++mi)
            af[mi] = *(const bf16x8*)&As[wm + mi * 16 + l16][kc];
        #pragma unroll
        for (int ni = 0; ni < 4; ++ni)
            bfg[ni] = *(const bf16x8*)&Bs[wn + ni * 16 + l16][kc];
        #pragma unroll
        for (int mi = 0; mi < 4; ++mi)
            #pragma unroll
            for (int ni = 0; ni < 4; ++ni)
                acc[mi][ni] = __builtin_amdgcn_mfma_f32_16x16x32_bf16(
                    af[mi], bfg[ni], acc[mi][ni], 0, 0, 0);
        __syncthreads();
    }

    #pragma unroll
    for (int mi = 0; mi < 4; ++mi) {
        const int row = m0 + wm + mi * 16 + lg * 4;
        #pragma unroll
        for (int ni = 0; ni < 4; ++ni) {
            const int col = n0 + wn + ni * 16 + l16;
            const float bv = bias[col];
            #pragma unroll
            for (int j = 0; j < 4; ++j)
                Cout[(long)(row + j) * DIM + col] = acc[mi][ni][j] + bv;
        }
    }
}

// Flash attention (round-9 structure) + T13 defer-max: skip the alpha-rescale
// path when the tile max stays within 8 of the running max (wave-uniform test).
__global__ __launch_bounds__(256, 4)
void attn_kernel(const short* __restrict__ Qp, const short* __restrict__ Kt,
                 const short* __restrict__ Vt, const float* __restrict__ bias,
                 const int* __restrict__ mask, short* __restrict__ Op) {
    __shared__ float Bsm[2][64][68];   // 34.8 KB

    const int d = blockIdx.x;
    const int lgc = (d & 7) * 192 + (d >> 3);   // XCD-contiguous (b,h) pairs
    const int qt = lgc & 15, pair = lgc >> 4;
    const int h = pair % NHEAD, b = pair / NHEAD;

    const int t = threadIdx.x, lane = t & 63, w = t >> 6;
    const int l16 = lane & 15, lg = lane >> 4;
    const int ql = w * 16 + l16;

    const int qrow = qt * 64 + ql;
    const short* qptr = Qp + (long)(b * SEQ + qrow) * DIM + h * HDIM + lg * 8;
    const bf16x8 qf0 = *(const bf16x8*)qptr;
    const bf16x8 qf1 = *(const bf16x8*)(qptr + 32);

    const short* ktile = Kt + (long)pair * 65536 + lane * 8;
    const short* vtile = Vt + (long)pair * 65536 + lane * 8;

    const int srow = t >> 4, scol = (t & 15) * 4;
    const float* bst = bias + ((long)pair * SEQ + qt * 64 + srow) * SEQ + scol;
    const int*   mst = mask + ((long)b * SEQ + qt * 64 + srow) * SEQ + scol;

    f32x4 acc_o[4] = {};
    float m_run = -1e30f, l_run = 0.f;
    constexpr float L2E = 1.4426950408889634f;

    f32x4 br[4]; i32x4 mr[4];

    auto issue_bm = [&](int kt) {
        #pragma unroll
        for (int i = 0; i < 4; ++i) {
            br[i] = __builtin_nontemporal_load((const f32x4*)(bst + (long)i * 16 * SEQ + kt * 64));
            mr[i] = *(const i32x4*)(mst + (long)i * 16 * SEQ + kt * 64);
        }
    };
    auto write_bm = [&](int buf) {
        #pragma unroll
        for (int i = 0; i < 4; ++i) {
            f32x4 o;
            #pragma unroll
            for (int j = 0; j < 4; ++j) o[j] = mr[i][j] ? br[i][j] : -1e30f;
            *(f32x4*)&Bsm[buf][i * 16 + srow][scol] = o;
        }
    };

    auto compute = [&](int kt, int buf) {
        const short* kf = ktile + kt * 4096;
        const short* vf = vtile + kt * 4096;
        short* prow = (short*)&Bsm[buf][ql][0];   // wave-private row in CUR buffer

        f32x4 s[4];
        __builtin_amdgcn_s_setprio(1);
        #pragma unroll
        for (int c = 0; c < 4; ++c) {
            const bf16x8 kb = *(const bf16x8*)(kf + c * 1024);
            f32x4 ci = *(const f32x4*)&Bsm[buf][ql][c * 16 + lg * 4];
            s[c] = __builtin_amdgcn_mfma_f32_16x16x32_bf16(kb, qf0, ci, 0, 0, 0);
        }
        #pragma unroll
        for (int c = 0; c < 4; ++c) {
            const bf16x8 kb = *(const bf16x8*)(kf + c * 1024 + 512);
            s[c] = __builtin_amdgcn_mfma_f32_16x16x32_bf16(kb, qf1, s[c], 0, 0, 0);
        }
        __builtin_amdgcn_s_setprio(0);

        float mt = -1e30f;
        #pragma unroll
        for (int c = 0; c < 4; ++c)
            #pragma unroll
            for (int j = 0; j < 4; ++j)
                mt = fmaxf(mt, s[c][j]);
        mt = fmaxf(mt, __shfl_xor(mt, 16));
        mt = fmaxf(mt, __shfl_xor(mt, 32));

        // T13 defer-max: only rescale when the max moved by more than 8
        if (!__all(mt - m_run <= 8.f)) {
            const float mn = fmaxf(m_run, mt);
            const float alpha = fexp2((m_run - mn) * L2E);
            m_run = mn;
            float al[4];
            #pragma unroll
            for (int j = 0; j < 4; ++j) al[j] = __shfl(alpha, lg * 4 + j);
            #pragma unroll
            for (int df = 0; df < 4; ++df)
                #pragma unroll
                for (int j = 0; j < 4; ++j)
                    acc_o[df][j] *= al[j];
            l_run *= alpha;
        }
        const float nm = -m_run * L2E;

        float lt = 0.f;
        #pragma unroll
        for (int c = 0; c < 4; ++c) {
            bf16x4 pk;
            #pragma unroll
            for (int j = 0; j < 4; ++j) {
                const float e = fexp2(fmaf(s[c][j], L2E, nm));
                lt += e;
                pk[j] = f2bf(e);
            }
            *(bf16x4*)(prow + c * 16 + lg * 4) = pk;
        }
        lt += __shfl_xor(lt, 16);
        lt += __shfl_xor(lt, 32);
        l_run += lt;

        const bf16x8 pa0 = *(const bf16x8*)(prow + lg * 8);
        const bf16x8 pa1 = *(const bf16x8*)(prow + 32 + lg * 8);
        __builtin_amdgcn_s_setprio(1);
        #pragma unroll
        for (int df = 0; df < 4; ++df) {
            const bf16x8 vb = *(const bf16x8*)(vf + df * 1024);
            acc_o[df] = __builtin_amdgcn_mfma_f32_16x16x32_bf16(pa0, vb, acc_o[df], 0, 0, 0);
        }
        #pragma unroll
        for (int df = 0; df < 4; ++df) {
            const bf16x8 vb = *(const bf16x8*)(vf + df * 1024 + 512);
            acc_o[df] = __builtin_amdgcn_mfma_f32_16x16x32_bf16(pa1, vb, acc_o[df], 0, 0, 0);
        }
        __builtin_amdgcn_s_setprio(0);
    };

    // prologue: tile 0 into buf0; tile 1 loads in flight
    issue_bm(0);
    write_bm(0);
    issue_bm(1);
    __syncthreads();

    int cur = 0;
    for (int kt = 0; kt < 16; ++kt) {
        compute(kt, cur);
        if (kt < 15) {
            write_bm(cur ^ 1);              // regs for kt+1 (issued a full iter ago)
            if (kt < 14) issue_bm(kt + 2);  // next-next: full-iter + barrier cover
            __syncthreads();
            cur ^= 1;
        }
    }

    float linv[4];
    #pragma unroll
    for (int j = 0; j < 4; ++j)
        linv[j] = 1.f / fmaxf(__shfl(l_run, lg * 4 + j), 1e-20f);

    #pragma unroll
    for (int df = 0; df < 4; ++df) {
        #pragma unroll
        for (int j = 0; j < 4; ++j) {
            const float val = acc_o[df][j] * linv[j];
            const int row = b * SEQ + qt * 64 + w * 16 + lg * 4 + j;
            const int col = h * HDIM + df * 16 + l16;
            Op[(long)row * DIM + col] = f2bf(val);
        }
    }
}

extern "C" void kernel_launch(void* const* d_in, const int* in_sizes, int n_in,
                              void* d_out, int out_size, void* d_ws, size_t ws_size,
                              hipStream_t stream) {
    const float* q         = (const float*)d_in[0];
    const float* k         = (const float*)d_in[1];
    const float* v         = (const float*)d_in[2];
    const float* attn_bias = (const float*)d_in[3];
    const int*   attn_mask = (const int*)d_in[4];
    const float* Wq = (const float*)d_in[5];
    const float* bq = (const float*)d_in[6];
    const float* Wk = (const float*)d_in[7];
    const float* bk = (const float*)d_in[8];
    const float* Wv = (const float*)d_in[9];
    const float* bv = (const float*)d_in[10];
    const float* Wo = (const float*)d_in[11];
    const float* bo = (const float*)d_in[12];
    float* out = (float*)d_out;

    const long NED = (long)MROWS * DIM;       // 6291456
    const long WED = (long)DIM * DIM;         // 589824
    short* Qp  = (short*)d_ws;                // [8192][768] bf16, pre-scaled 1/8
    short* Kp  = Qp + NED;                    // K fragment-order [96][16][4096]
    short* Vp  = Kp + NED;                    // V fragment-order [96][16][4096]
    short* Op  = Vp + NED;
    short* qb  = Op + NED;                    // bf16 inputs
    short* kb  = qb + NED;
    short* vb  = kb + NED;
    short* Wqb = vb + NED;                    // bf16 weights
    short* Wkb = Wqb + WED;
    short* Wvb = Wkb + WED;
    short* Wob = Wvb + WED;

    const dim3 blk(256);

    cvt_all<<<2048, blk, 0, stream>>>(q, k, v, Wq, Wk, Wv, Wo,
                                      qb, kb, vb, Wqb, Wkb, Wvb, Wob,
                                      (int)(NED / 8), (int)(WED / 8));

    const int gemm_grid = (MROWS / 128) * (DIM / 128);   // 384
    gemm_qkv<<<3 * gemm_grid, blk, 0, stream>>>(qb, kb, vb, Wqb, Wkb, Wvb,
                                                bq, bk, bv, Qp, Kp, Vp);

    const int attn_grid = BATCH * NHEAD * (SEQ / 64);    // 1536
    attn_kernel<<<attn_grid, blk, 0, stream>>>(Qp, Kp, Vp, attn_bias, attn_mask, Op);

    gemm_out<<<gemm_grid, blk, 0, stream>>>(Op, Wob, bo, out);
}

// Round 13
// 250.602 us; speedup vs baseline: 1.2015x; 1.0268x over previous
//
#include <hip/hip_runtime.h>
#include <hip/hip_bf16.h>

using f32x4  = __attribute__((ext_vector_type(4))) float;
using i32x4  = __attribute__((ext_vector_type(4))) int;
using bf16x8 = __attribute__((ext_vector_type(8))) short;
using bf16x4 = __attribute__((ext_vector_type(4))) short;

constexpr int BATCH = 8, SEQ = 1024, DIM = 768, NHEAD = 12, HDIM = 64;
constexpr int MROWS = BATCH * SEQ;   // 8192

__device__ __forceinline__ short f2bf(float f) {
    union { float f; unsigned u; } x; x.f = f;
    unsigned r = (x.u + 0x7fffu + ((x.u >> 16) & 1u)) >> 16;
    return (short)r;
}
__device__ __forceinline__ float fexp2(float x) { return __builtin_amdgcn_exp2f(x); }

// async global->LDS, 16B per lane; LDS dest = wave-uniform base + lane*16
__device__ __forceinline__ void gload_lds16(const void* g, void* l) {
    __builtin_amdgcn_global_load_lds(
        (const __attribute__((address_space(1))) void*)g,
        (__attribute__((address_space(3))) void*)l, 16, 0, 0);
}

__device__ __forceinline__ bf16x8 cvt8(const float* p) {
    const f32x4 x0 = *(const f32x4*)p;
    const f32x4 x1 = *(const f32x4*)(p + 4);
    bf16x8 r;
    #pragma unroll
    for (int j = 0; j < 4; ++j) { r[j] = f2bf(x0[j]); r[4 + j] = f2bf(x1[j]); }
    return r;
}

// K fragment-order: attn reads kb[c][ks] at kt*4096 + c*1024 + ks*512 + lane*8
// (l16 = key&15, lg = hd-slot). Element (tok, dd):
__device__ __forceinline__ long kfrag_addr(int tok, int dd) {
    return ((long)(tok >> 6)) * 4096 + ((tok & 63) >> 4) * 1024 + (dd >> 5) * 512
         + ((dd >> 3) & 3) * 128 + (tok & 15) * 8 + (dd & 7);
}
// V fragment-order: attn reads vb[df][ks] at kt*4096 + df*1024 + ks*512 + lane*8
// (l16 = hd&15, lg = key-slot). Element (tok, dd):
__device__ __forceinline__ long vfrag_addr(int tok, int dd) {
    return ((long)(tok >> 6)) * 4096 + (dd >> 4) * 1024 + ((tok >> 5) & 1) * 512
         + ((tok >> 3) & 3) * 128 + (dd & 15) * 8 + (tok & 7);
}

// single fp32->bf16 prepass: 3 big arrays + 4 weight arrays in one launch
__global__ __launch_bounds__(256)
void cvt_all(const float* __restrict__ q, const float* __restrict__ k,
             const float* __restrict__ v,
             const float* __restrict__ Wq, const float* __restrict__ Wk,
             const float* __restrict__ Wv, const float* __restrict__ Wo,
             short* __restrict__ qb, short* __restrict__ kb, short* __restrict__ vb,
             short* __restrict__ Wqb, short* __restrict__ Wkb,
             short* __restrict__ Wvb, short* __restrict__ Wob,
             int nbig8, int nsml8) {
    const int stride = gridDim.x * 256;
    for (int i = blockIdx.x * 256 + threadIdx.x; i < nbig8; i += stride) {
        const long base = (long)i * 8;
        *(bf16x8*)(qb + base) = cvt8(q + base);
        *(bf16x8*)(kb + base) = cvt8(k + base);
        *(bf16x8*)(vb + base) = cvt8(v + base);
    }
    for (int i = blockIdx.x * 256 + threadIdx.x; i < nsml8; i += stride) {
        const long base = (long)i * 8;
        *(bf16x8*)(Wqb + base) = cvt8(Wq + base);
        *(bf16x8*)(Wkb + base) = cvt8(Wk + base);
        *(bf16x8*)(Wvb + base) = cvt8(Wv + base);
        *(bf16x8*)(Wob + base) = cvt8(Wo + base);
    }
}

// Fused Q/K/V projection, m97-style staging: global_load_lds width=16,
// linear LDS [128][32], 2 barriers per K-step. sub = bid%3 interleave.
__global__ __launch_bounds__(256, 4)
void gemm_qkv(const short* __restrict__ qb, const short* __restrict__ kb,
              const short* __restrict__ vbp,
              const short* __restrict__ Wqb, const short* __restrict__ Wkb,
              const short* __restrict__ Wvb,
              const float* __restrict__ bq, const float* __restrict__ bk,
              const float* __restrict__ bv,
              short* __restrict__ Qp, short* __restrict__ Kp, short* __restrict__ Vp) {
    constexpr int K  = DIM;
    constexpr int NT = DIM / 128;
    __shared__ alignas(16) short As[128][32];
    __shared__ alignas(16) short Bs[128][32];

    const int sub = blockIdx.x % 3;
    const int bid = blockIdx.x / 3;
    const short* A = sub == 0 ? qb : sub == 1 ? kb : vbp;
    const short* W = sub == 0 ? Wqb : sub == 1 ? Wkb : Wvb;
    const float* bias = sub == 0 ? bq : sub == 1 ? bk : bv;

    const int bm = bid / NT, bn = bid % NT;
    const int m0 = bm * 128, n0 = bn * 128;
    const int t = threadIdx.x;
    const int lane = t & 63, w = t >> 6;
    const int wm = (w >> 1) * 64, wn = (w & 1) * 64;
    const int l16 = lane & 15, lg = lane >> 4;

    // staging map: wave w covers rows [w*32, w*32+32); lane -> row w*32+p*16+(lane>>2),
    // col elems (lane&3)*8 (16B). LDS dest base wave-uniform.
    const int lrow = lane >> 2, lcol = (lane & 3) * 8;
    const short* ag = A + (long)(m0 + w * 32 + lrow) * K + lcol;
    const short* wg = W + (long)(n0 + w * 32 + lrow) * K + lcol;
    short* lA0 = &As[w * 32][0];
    short* lA1 = &As[w * 32 + 16][0];
    short* lB0 = &Bs[w * 32][0];
    short* lB1 = &Bs[w * 32 + 16][0];

    f32x4 acc[4][4] = {};

    for (int k0 = 0; k0 < K; k0 += 32) {
        gload_lds16(ag + k0, lA0);
        gload_lds16(ag + (long)16 * K + k0, lA1);
        gload_lds16(wg + k0, lB0);
        gload_lds16(wg + (long)16 * K + k0, lB1);
        __syncthreads();   // vmcnt(0) drain + all waves staged

        bf16x8 af[4], bfg[4];
        const int kc = lg * 8;
        #pragma unroll
        for (int mi = 0; mi < 4; ++mi)
            af[mi] = *(const bf16x8*)&As[wm + mi * 16 + l16][kc];
        #pragma unroll
        for (int ni = 0; ni < 4; ++ni)
            bfg[ni] = *(const bf16x8*)&Bs[wn + ni * 16 + l16][kc];
        #pragma unroll
        for (int mi = 0; mi < 4; ++mi)
            #pragma unroll
            for (int ni = 0; ni < 4; ++ni)
                acc[mi][ni] = __builtin_amdgcn_mfma_f32_16x16x32_bf16(
                    af[mi], bfg[ni], acc[mi][ni], 0, 0, 0);
        __syncthreads();   // compute done before next stage overwrites
    }

    #pragma unroll
    for (int mi = 0; mi < 4; ++mi) {
        const int row = m0 + wm + mi * 16 + lg * 4;
        const int bb = row / SEQ;
        #pragma unroll
        for (int ni = 0; ni < 4; ++ni) {
            const int col = n0 + wn + ni * 16 + l16;
            const float bv = bias[col];
            const int hh = col >> 6, dd = col & 63;
            #pragma unroll
            for (int j = 0; j < 4; ++j) {
                float val = acc[mi][ni][j] + bv;
                if (sub == 0) {
                    Qp[(long)(row + j) * DIM + col] = f2bf(val * 0.125f);
                } else {
                    const int tok = (row % SEQ) + j;
                    const long pbase = (long)(bb * NHEAD + hh) * 65536;
                    if (sub == 1)
                        Kp[pbase + kfrag_addr(tok, dd)] = f2bf(val);
                    else
                        Vp[pbase + vfrag_addr(tok, dd)] = f2bf(val);
                }
            }
        }
    }
}

// Output projection, same m97-style staging. C fp32 = A(bf16) @ W^T + bias
__global__ __launch_bounds__(256, 4)
void gemm_out(const short* __restrict__ A, const short* __restrict__ W,
              const float* __restrict__ bias, float* __restrict__ Cout) {
    constexpr int K  = DIM;
    constexpr int NT = DIM / 128;
    __shared__ alignas(16) short As[128][32];
    __shared__ alignas(16) short Bs[128][32];

    const int bm = blockIdx.x / NT, bn = blockIdx.x % NT;
    const int m0 = bm * 128, n0 = bn * 128;
    const int t = threadIdx.x;
    const int lane = t & 63, w = t >> 6;
    const int wm = (w >> 1) * 64, wn = (w & 1) * 64;
    const int l16 = lane & 15, lg = lane >> 4;

    const int lrow = lane >> 2, lcol = (lane & 3) * 8;
    const short* ag = A + (long)(m0 + w * 32 + lrow) * K + lcol;
    const short* wg = W + (long)(n0 + w * 32 + lrow) * K + lcol;
    short* lA0 = &As[w * 32][0];
    short* lA1 = &As[w * 32 + 16][0];
    short* lB0 = &Bs[w * 32][0];
    short* lB1 = &Bs[w * 32 + 16][0];

    f32x4 acc[4][4] = {};

    for (int k0 = 0; k0 < K; k0 += 32) {
        gload_lds16(ag + k0, lA0);
        gload_lds16(ag + (long)16 * K + k0, lA1);
        gload_lds16(wg + k0, lB0);
        gload_lds16(wg + (long)16 * K + k0, lB1);
        __syncthreads();

        bf16x8 af[4], bfg[4];
        const int kc = lg * 8;
        #pragma unroll
        for (int mi = 0; mi < 4; ++mi)
            af[mi] = *(const bf16x8*)&As[wm + mi * 16 + l16][kc];
        #pragma unroll
        for (int ni = 0; ni < 4; ++ni)
            bfg[ni] = *(const bf16x8*)&Bs[wn + ni * 16 + l16][kc];
        #pragma unroll
        for (int mi = 0; mi < 4; ++mi)
            #pragma unroll
            for (int ni = 0; ni < 4; ++ni)
                acc[mi][ni] = __builtin_amdgcn_mfma_f32_16x16x32_bf16(
                    af[mi], bfg[ni], acc[mi][ni], 0, 0, 0);
        __syncthreads();
    }

    #pragma unroll
    for (int mi = 0; mi < 4; ++mi) {
        const int row = m0 + wm + mi * 16 + lg * 4;
        #pragma unroll
        for (int ni = 0; ni < 4; ++ni) {
            const int col = n0 + wn + ni * 16 + l16;
            const float bv = bias[col];
            #pragma unroll
            for (int j = 0; j < 4; ++j)
                Cout[(long)(row + j) * DIM + col] = acc[mi][ni][j] + bv;
        }
    }
}

// Flash attention (round-12, unchanged): fragment-ordered K/V direct loads,
// double-buffered masked-bias LDS, P aliased into CUR rows, T13 defer-max.
__global__ __launch_bounds__(256, 4)
void attn_kernel(const short* __restrict__ Qp, const short* __restrict__ Kt,
                 const short* __restrict__ Vt, const float* __restrict__ bias,
                 const int* __restrict__ mask, short* __restrict__ Op) {
    __shared__ float Bsm[2][64][68];   // 34.8 KB

    const int d = blockIdx.x;
    const int lgc = (d & 7) * 192 + (d >> 3);   // XCD-contiguous (b,h) pairs
    const int qt = lgc & 15, pair = lgc >> 4;
    const int h = pair % NHEAD, b = pair / NHEAD;

    const int t = threadIdx.x, lane = t & 63, w = t >> 6;
    const int l16 = lane & 15, lg = lane >> 4;
    const int ql = w * 16 + l16;

    const int qrow = qt * 64 + ql;
    const short* qptr = Qp + (long)(b * SEQ + qrow) * DIM + h * HDIM + lg * 8;
    const bf16x8 qf0 = *(const bf16x8*)qptr;
    const bf16x8 qf1 = *(const bf16x8*)(qptr + 32);

    const short* ktile = Kt + (long)pair * 65536 + lane * 8;
    const short* vtile = Vt + (long)pair * 65536 + lane * 8;

    const int srow = t >> 4, scol = (t & 15) * 4;
    const float* bst = bias + ((long)pair * SEQ + qt * 64 + srow) * SEQ + scol;
    const int*   mst = mask + ((long)b * SEQ + qt * 64 + srow) * SEQ + scol;

    f32x4 acc_o[4] = {};
    float m_run = -1e30f, l_run = 0.f;
    constexpr float L2E = 1.4426950408889634f;

    f32x4 br[4]; i32x4 mr[4];

    auto issue_bm = [&](int kt) {
        #pragma unroll
        for (int i = 0; i < 4; ++i) {
            br[i] = __builtin_nontemporal_load((const f32x4*)(bst + (long)i * 16 * SEQ + kt * 64));
            mr[i] = *(const i32x4*)(mst + (long)i * 16 * SEQ + kt * 64);
        }
    };
    auto write_bm = [&](int buf) {
        #pragma unroll
        for (int i = 0; i < 4; ++i) {
            f32x4 o;
            #pragma unroll
            for (int j = 0; j < 4; ++j) o[j] = mr[i][j] ? br[i][j] : -1e30f;
            *(f32x4*)&Bsm[buf][i * 16 + srow][scol] = o;
        }
    };

    auto compute = [&](int kt, int buf) {
        const short* kf = ktile + kt * 4096;
        const short* vf = vtile + kt * 4096;
        short* prow = (short*)&Bsm[buf][ql][0];   // wave-private row in CUR buffer

        f32x4 s[4];
        __builtin_amdgcn_s_setprio(1);
        #pragma unroll
        for (int c = 0; c < 4; ++c) {
            const bf16x8 kb = *(const bf16x8*)(kf + c * 1024);
            f32x4 ci = *(const f32x4*)&Bsm[buf][ql][c * 16 + lg * 4];
            s[c] = __builtin_amdgcn_mfma_f32_16x16x32_bf16(kb, qf0, ci, 0, 0, 0);
        }
        #pragma unroll
        for (int c = 0; c < 4; ++c) {
            const bf16x8 kb = *(const bf16x8*)(kf + c * 1024 + 512);
            s[c] = __builtin_amdgcn_mfma_f32_16x16x32_bf16(kb, qf1, s[c], 0, 0, 0);
        }
        __builtin_amdgcn_s_setprio(0);

        float mt = -1e30f;
        #pragma unroll
        for (int c = 0; c < 4; ++c)
            #pragma unroll
            for (int j = 0; j < 4; ++j)
                mt = fmaxf(mt, s[c][j]);
        mt = fmaxf(mt, __shfl_xor(mt, 16));
        mt = fmaxf(mt, __shfl_xor(mt, 32));

        // T13 defer-max: only rescale when the max moved by more than 8
        if (!__all(mt - m_run <= 8.f)) {
            const float mn = fmaxf(m_run, mt);
            const float alpha = fexp2((m_run - mn) * L2E);
            m_run = mn;
            float al[4];
            #pragma unroll
            for (int j = 0; j < 4; ++j) al[j] = __shfl(alpha, lg * 4 + j);
            #pragma unroll
            for (int df = 0; df < 4; ++df)
                #pragma unroll
                for (int j = 0; j < 4; ++j)
                    acc_o[df][j] *= al[j];
            l_run *= alpha;
        }
        const float nm = -m_run * L2E;

        float lt = 0.f;
        #pragma unroll
        for (int c = 0; c < 4; ++c) {
            bf16x4 pk;
            #pragma unroll
            for (int j = 0; j < 4; ++j) {
                const float e = fexp2(fmaf(s[c][j], L2E, nm));
                lt += e;
                pk[j] = f2bf(e);
            }
            *(bf16x4*)(prow + c * 16 + lg * 4) = pk;
        }
        lt += __shfl_xor(lt, 16);
        lt += __shfl_xor(lt, 32);
        l_run += lt;

        const bf16x8 pa0 = *(const bf16x8*)(prow + lg * 8);
        const bf16x8 pa1 = *(const bf16x8*)(prow + 32 + lg * 8);
        __builtin_amdgcn_s_setprio(1);
        #pragma unroll
        for (int df = 0; df < 4; ++df) {
            const bf16x8 vb = *(const bf16x8*)(vf + df * 1024);
            acc_o[df] = __builtin_amdgcn_mfma_f32_16x16x32_bf16(pa0, vb, acc_o[df], 0, 0, 0);
        }
        #pragma unroll
        for (int df = 0; df < 4; ++df) {
            const bf16x8 vb = *(const bf16x8*)(vf + df * 1024 + 512);
            acc_o[df] = __builtin_amdgcn_mfma_f32_16x16x32_bf16(pa1, vb, acc_o[df], 0, 0, 0);
        }
        __builtin_amdgcn_s_setprio(0);
    };

    // prologue: tile 0 into buf0; tile 1 loads in flight
    issue_bm(0);
    write_bm(0);
    issue_bm(1);
    __syncthreads();

    int cur = 0;
    for (int kt = 0; kt < 16; ++kt) {
        compute(kt, cur);
        if (kt < 15) {
            write_bm(cur ^ 1);              // regs for kt+1 (issued a full iter ago)
            if (kt < 14) issue_bm(kt + 2);  // next-next: full-iter + barrier cover
            __syncthreads();
            cur ^= 1;
        }
    }

    float linv[4];
    #pragma unroll
    for (int j = 0; j < 4; ++j)
        linv[j] = 1.f / fmaxf(__shfl(l_run, lg * 4 + j), 1e-20f);

    #pragma unroll
    for (int df = 0; df < 4; ++df) {
        #pragma unroll
        for (int j = 0; j < 4; ++j) {
            const float val = acc_o[df][j] * linv[j];
            const int row = b * SEQ + qt * 64 + w * 16 + lg * 4 + j;
            const int col = h * HDIM + df * 16 + l16;
            Op[(long)row * DIM + col] = f2bf(val);
        }
    }
}

extern "C" void kernel_launch(void* const* d_in, const int* in_sizes, int n_in,
                              void* d_out, int out_size, void* d_ws, size_t ws_size,
                              hipStream_t stream) {
    const float* q         = (const float*)d_in[0];
    const float* k         = (const float*)d_in[1];
    const float* v         = (const float*)d_in[2];
    const float* attn_bias = (const float*)d_in[3];
    const int*   attn_mask = (const int*)d_in[4];
    const float* Wq = (const float*)d_in[5];
    const float* bq = (const float*)d_in[6];
    const float* Wk = (const float*)d_in[7];
    const float* bk = (const float*)d_in[8];
    const float* Wv = (const float*)d_in[9];
    const float* bv = (const float*)d_in[10];
    const float* Wo = (const float*)d_in[11];
    const float* bo = (const float*)d_in[12];
    float* out = (float*)d_out;

    const long NED = (long)MROWS * DIM;       // 6291456
    const long WED = (long)DIM * DIM;         // 589824
    short* Qp  = (short*)d_ws;                // [8192][768] bf16, pre-scaled 1/8
    short* Kp  = Qp + NED;                    // K fragment-order [96][16][4096]
    short* Vp  = Kp + NED;                    // V fragment-order [96][16][4096]
    short* Op  = Vp + NED;
    short* qb  = Op + NED;                    // bf16 inputs
    short* kb  = qb + NED;
    short* vb  = kb + NED;
    short* Wqb = vb + NED;                    // bf16 weights
    short* Wkb = Wqb + WED;
    short* Wvb = Wkb + WED;
    short* Wob = Wvb + WED;

    const dim3 blk(256);

    cvt_all<<<2048, blk, 0, stream>>>(q, k, v, Wq, Wk, Wv, Wo,
                                      qb, kb, vb, Wqb, Wkb, Wvb, Wob,
                                      (int)(NED / 8), (int)(WED / 8));

    const int gemm_grid = (MROWS / 128) * (DIM / 128);   // 384
    gemm_qkv<<<3 * gemm_grid, blk, 0, stream>>>(qb, kb, vb, Wqb, Wkb, Wvb,
                                                bq, bk, bv, Qp, Kp, Vp);

    const int attn_grid = BATCH * NHEAD * (SEQ / 64);    // 1536
    attn_kernel<<<attn_grid, blk, 0, stream>>>(Qp, Kp, Vp, attn_bias, attn_mask, Op);

    gemm_out<<<gemm_grid, blk, 0, stream>>>(Op, Wob, bo, out);
}